// Round 7
// baseline (273.191 us; speedup 1.0000x reference)
//
#include <hip/hip_runtime.h>

// Problem constants
#define B     4
#define LQ    4096
#define LK    5119
#define LKP   5120              // per-batch padded rows (160 chunks of 32)
#define D     512
#define CACHE 1024
#define MQ    (B * LQ)          // 16384 = 128*128
#define MKP   (B * LKP)         // 20480 = 160*128
#define NCH   160               // 32-row chunks per batch
#define TI    32                // query rows per window block

typedef float  f32x4  __attribute__((ext_vector_type(4)));
typedef __bf16 bf16x2 __attribute__((ext_vector_type(2)));
typedef __bf16 bf16x8 __attribute__((ext_vector_type(8)));

// async global->LDS, 16B per lane; lds base wave-uniform (HW adds lane*16)
__device__ __forceinline__ void async16(void* lds, const void* g)
{
    __builtin_amdgcn_global_load_lds(
        (__attribute__((address_space(1))) void*)(g),
        (__attribute__((address_space(3))) void*)(lds),
        16, 0, 0);
}

// ---------------------------------------------------------------------------
// Kernel 1 (prep): z in {0,1,2}: LayerNorm -> bf16 (half-wave per row,
// 8 rows/block).  k/v outputs use per-batch-padded layout (stride LKP rows,
// row 5119 of each batch left unwritten).  z == 3: weight transpose f32->bf16.
// All intermediate stores are non-temporal (flush past per-XCD L2 so the
// consumer kernel's cross-XCD reads hit clean L3 lines).
// ---------------------------------------------------------------------------
__global__ __launch_bounds__(256) void prep_kernel(
    const float* __restrict__ q, const float* __restrict__ k,
    const float* __restrict__ v,
    const float* __restrict__ gq, const float* __restrict__ bq,
    const float* __restrict__ gk, const float* __restrict__ bk,
    const float* __restrict__ gv, const float* __restrict__ bv,
    const float* __restrict__ Wq, const float* __restrict__ Wk,
    const float* __restrict__ Wv,
    __bf16* __restrict__ qn, __bf16* __restrict__ kn, __bf16* __restrict__ vn,
    __bf16* __restrict__ wtq, __bf16* __restrict__ wtk, __bf16* __restrict__ wtv)
{
    const int z = blockIdx.y;

    if (z == 3) {               // ---- weight transpose-convert ----
        const int idx = blockIdx.x;
        if (idx >= 384) return;
        const int zz  = idx >> 7;        // 0..2
        const int rem = idx & 127;
        const float* W = (zz == 0) ? Wq : (zz == 1) ? Wk : Wv;
        __bf16*     Wt = (zz == 0) ? wtq : (zz == 1) ? wtk : wtv;
        const int n  = (rem & 1) * 256 + threadIdx.x;
        const int k0 = (rem >> 1) * 8;
        bf16x8 o;
#pragma unroll
        for (int j = 0; j < 8; ++j)
            o[j] = (__bf16)W[(long)(k0 + j) * D + n];
        __builtin_nontemporal_store(
            o, reinterpret_cast<bf16x8*>(Wt + (long)n * D + k0));
        return;
    }

    // ---- LayerNorm ----
    const float *x, *g, *bb; __bf16* o;
    if (z == 0)      { x = q; g = gq; bb = bq; o = qn; }
    else if (z == 1) { x = k; g = gk; bb = bk; o = kn; }
    else             { x = v; g = gv; bb = bv; o = vn; }

    const int rp = blockIdx.x * 8 + (threadIdx.x >> 5);   // padded row id
    long rin;
    if (z == 0) {
        if (rp >= MQ) return;
        rin = rp;
    } else {
        const int bch = rp / LKP;
        const int i   = rp - bch * LKP;
        if (i == LK) return;            // per-batch pad row, leave garbage
        rin = (long)bch * LK + i;
    }

    const int c0 = (threadIdx.x & 31) * 16;
    const float* xr = x + rin * D + c0;

    float4 a[4];
#pragma unroll
    for (int j = 0; j < 4; ++j)
        a[j] = *reinterpret_cast<const float4*>(xr + j * 4);

    float s = 0.f, ss = 0.f;
#pragma unroll
    for (int j = 0; j < 4; ++j) {
        s  += a[j].x + a[j].y + a[j].z + a[j].w;
        ss += a[j].x*a[j].x + a[j].y*a[j].y + a[j].z*a[j].z + a[j].w*a[j].w;
    }
#pragma unroll
    for (int m = 1; m <= 16; m <<= 1) {     // reduce within 32-lane half
        s  += __shfl_xor(s,  m, 64);
        ss += __shfl_xor(ss, m, 64);
    }
    const float mean = s * (1.f / (float)D);
    const float var  = ss * (1.f / (float)D) - mean * mean;
    const float rs   = rsqrtf(var + 1e-5f);

    bf16x8 o0, o1;
#pragma unroll
    for (int j = 0; j < 4; ++j) {
        const float4 gv4 = *reinterpret_cast<const float4*>(g  + c0 + j * 4);
        const float4 bv4 = *reinterpret_cast<const float4*>(bb + c0 + j * 4);
        const float y0 = (a[j].x - mean) * rs * gv4.x + bv4.x;
        const float y1 = (a[j].y - mean) * rs * gv4.y + bv4.y;
        const float y2 = (a[j].z - mean) * rs * gv4.z + bv4.z;
        const float y3 = (a[j].w - mean) * rs * gv4.w + bv4.w;
        if (j < 2) {
            o0[j*4+0] = (__bf16)y0; o0[j*4+1] = (__bf16)y1;
            o0[j*4+2] = (__bf16)y2; o0[j*4+3] = (__bf16)y3;
        } else {
            o1[(j-2)*4+0] = (__bf16)y0; o1[(j-2)*4+1] = (__bf16)y1;
            o1[(j-2)*4+2] = (__bf16)y2; o1[(j-2)*4+3] = (__bf16)y3;
        }
    }
    __bf16* orow = o + (long)rp * D + c0;
    __builtin_nontemporal_store(o0, reinterpret_cast<bf16x8*>(orow));
    __builtin_nontemporal_store(o1, reinterpret_cast<bf16x8*>(orow + 8));
}

// ---------------------------------------------------------------------------
// Kernel 2 (gemm_fused): bid < 512 -> qp = relu(qn@Wq + bwq) (128x128 tile);
// bid >= 512 -> kv = relu(kn@Wk + bwk) * (vn@Wv + bwv) (128x64 tile) with
// fused 32-row chunk sums stored to Csum.  Both paths use ntile-INNER block
// order so consecutive blocks share the same A-tile (L2/L3 locality).
// BK=64, async16 staging, XOR-swizzled 16B chunks (conflict-free).
// ---------------------------------------------------------------------------
__global__ __launch_bounds__(256, 2) void gemm_fused_kernel(
    const __bf16* __restrict__ qn, const __bf16* __restrict__ kn,
    const __bf16* __restrict__ vn,
    const __bf16* __restrict__ wtq, const __bf16* __restrict__ wtk,
    const __bf16* __restrict__ wtv,
    const float* __restrict__ bwq, const float* __restrict__ bwk,
    const float* __restrict__ bwv,
    __bf16* __restrict__ qpb, __bf16* __restrict__ kvb,
    float* __restrict__ Csum)
{
    __shared__ __attribute__((aligned(16))) __bf16 smem[24576];  // 48 KB

    const int bid  = blockIdx.x;
    const int tid  = threadIdx.x;
    const int lane = tid & 63;
    const int wave = tid >> 6;
    const int quad = lane >> 4;
    const int l16  = lane & 15;
    const int wm   = wave >> 1;
    const int wn   = wave & 1;
    const int lrow = lane >> 3;                    // 0..7
    const int lcs  = ((lane & 7) ^ lrow) * 8;      // swizzled k-col (bf16)

    if (bid < 512) {
        // ================= q GEMM: 128x128 tile =================
        __bf16* As = smem;                // 128*64
        __bf16* Bs = smem + 8192;         // 128*64

        f32x4 acc[4][4];
#pragma unroll
        for (int i = 0; i < 4; ++i)
#pragma unroll
            for (int j = 0; j < 4; ++j)
                acc[i][j] = (f32x4){0.f, 0.f, 0.f, 0.f};

        const long arow0 = (long)(bid >> 2) * 128;
        const long brow0 = (long)(bid & 3) * 128;

        for (int k0 = 0; k0 < D; k0 += 64) {
#pragma unroll
            for (int j = 0; j < 4; ++j) {
                const int r0  = (j * 4 + wave) * 8;
                const int row = r0 + lrow;
                async16(&As[r0 * 64], &qn [(arow0 + row) * D + k0 + lcs]);
                async16(&Bs[r0 * 64], &wtq[(brow0 + row) * D + k0 + lcs]);
            }
            __syncthreads();

            bf16x8 af[4][2], bf[4][2];
#pragma unroll
            for (int tm = 0; tm < 4; ++tm) {
                const int m = wm * 64 + tm * 16 + l16;
#pragma unroll
                for (int kh = 0; kh < 2; ++kh)
                    af[tm][kh] = *reinterpret_cast<const bf16x8*>(
                        &As[m * 64 + (((kh * 4 + quad) ^ (m & 7)) * 8)]);
            }
#pragma unroll
            for (int tn = 0; tn < 4; ++tn) {
                const int n = wn * 64 + tn * 16 + l16;
#pragma unroll
                for (int kh = 0; kh < 2; ++kh)
                    bf[tn][kh] = *reinterpret_cast<const bf16x8*>(
                        &Bs[n * 64 + (((kh * 4 + quad) ^ (n & 7)) * 8)]);
            }
#pragma unroll
            for (int kh = 0; kh < 2; ++kh)
#pragma unroll
                for (int tm = 0; tm < 4; ++tm)
#pragma unroll
                    for (int tn = 0; tn < 4; ++tn)
                        acc[tm][tn] = __builtin_amdgcn_mfma_f32_16x16x32_bf16(
                            af[tm][kh], bf[tn][kh], acc[tm][tn], 0, 0, 0);
            __syncthreads();
        }

#pragma unroll
        for (int tm = 0; tm < 4; ++tm) {
            const long row0 = arow0 + wm * 64 + tm * 16 + quad * 4;
#pragma unroll
            for (int tn = 0; tn < 4; ++tn) {
                const int col = (int)brow0 + wn * 64 + tn * 16 + l16;
                const float bv = bwq[col];
#pragma unroll
                for (int r = 0; r < 4; ++r)
                    __builtin_nontemporal_store(
                        (__bf16)fmaxf(acc[tm][tn][r] + bv, 0.f),
                        &qpb[(row0 + r) * D + col]);
            }
        }
    } else {
        // ================= kv dual GEMM: 128x64 tile =================
        __bf16* Ks  = smem;               // 128*64
        __bf16* Vs  = smem + 8192;        // 128*64
        __bf16* WKs = smem + 16384;       // 64*64
        __bf16* WVs = smem + 20480;       // 64*64

        const int bid2  = bid - 512;
        const int mtile = bid2 >> 3;      // ntile-inner: 8 consecutive blocks
        const int ntile = bid2 & 7;       // share one 128-row A-tile

        f32x4 acck[4][2], accv[4][2];
#pragma unroll
        for (int i = 0; i < 4; ++i)
#pragma unroll
            for (int j = 0; j < 2; ++j) {
                acck[i][j] = (f32x4){0.f, 0.f, 0.f, 0.f};
                accv[i][j] = (f32x4){0.f, 0.f, 0.f, 0.f};
            }

        const long arow0 = (long)mtile * 128;
        const long brow0 = (long)ntile * 64;

        for (int k0 = 0; k0 < D; k0 += 64) {
#pragma unroll
            for (int j = 0; j < 4; ++j) {
                const int r0  = (j * 4 + wave) * 8;
                const int row = r0 + lrow;
                async16(&Ks[r0 * 64], &kn[(arow0 + row) * D + k0 + lcs]);
                async16(&Vs[r0 * 64], &vn[(arow0 + row) * D + k0 + lcs]);
            }
#pragma unroll
            for (int j = 0; j < 2; ++j) {
                const int r0  = (j * 4 + wave) * 8;
                const int row = r0 + lrow;
                async16(&WKs[r0 * 64], &wtk[(brow0 + row) * D + k0 + lcs]);
                async16(&WVs[r0 * 64], &wtv[(brow0 + row) * D + k0 + lcs]);
            }
            __syncthreads();

            bf16x8 fa[4][2], fb[2][2];
#pragma unroll
            for (int tm = 0; tm < 4; ++tm) {
                const int m = wm * 64 + tm * 16 + l16;
#pragma unroll
                for (int kh = 0; kh < 2; ++kh)
                    fa[tm][kh] = *reinterpret_cast<const bf16x8*>(
                        &Ks[m * 64 + (((kh * 4 + quad) ^ (m & 7)) * 8)]);
            }
#pragma unroll
            for (int tn = 0; tn < 2; ++tn) {
                const int n = wn * 32 + tn * 16 + l16;
#pragma unroll
                for (int kh = 0; kh < 2; ++kh)
                    fb[tn][kh] = *reinterpret_cast<const bf16x8*>(
                        &WKs[n * 64 + (((kh * 4 + quad) ^ (n & 7)) * 8)]);
            }
#pragma unroll
            for (int kh = 0; kh < 2; ++kh)
#pragma unroll
                for (int tm = 0; tm < 4; ++tm)
#pragma unroll
                    for (int tn = 0; tn < 2; ++tn)
                        acck[tm][tn] = __builtin_amdgcn_mfma_f32_16x16x32_bf16(
                            fa[tm][kh], fb[tn][kh], acck[tm][tn], 0, 0, 0);
#pragma unroll
            for (int tm = 0; tm < 4; ++tm) {
                const int m = wm * 64 + tm * 16 + l16;
#pragma unroll
                for (int kh = 0; kh < 2; ++kh)
                    fa[tm][kh] = *reinterpret_cast<const bf16x8*>(
                        &Vs[m * 64 + (((kh * 4 + quad) ^ (m & 7)) * 8)]);
            }
#pragma unroll
            for (int tn = 0; tn < 2; ++tn) {
                const int n = wn * 32 + tn * 16 + l16;
#pragma unroll
                for (int kh = 0; kh < 2; ++kh)
                    fb[tn][kh] = *reinterpret_cast<const bf16x8*>(
                        &WVs[n * 64 + (((kh * 4 + quad) ^ (n & 7)) * 8)]);
            }
#pragma unroll
            for (int kh = 0; kh < 2; ++kh)
#pragma unroll
                for (int tm = 0; tm < 4; ++tm)
#pragma unroll
                    for (int tn = 0; tn < 2; ++tn)
                        accv[tm][tn] = __builtin_amdgcn_mfma_f32_16x16x32_bf16(
                            fa[tm][kh], fb[tn][kh], accv[tm][tn], 0, 0, 0);
            __syncthreads();
        }

        // epilogue: write kv (bf16) and accumulate 32-row chunk partials
        float part[2][2] = {{0.f, 0.f}, {0.f, 0.f}};   // [tn][tm>>1]
#pragma unroll
        for (int tm = 0; tm < 4; ++tm) {
            const long row0 = arow0 + wm * 64 + tm * 16 + quad * 4;
#pragma unroll
            for (int tn = 0; tn < 2; ++tn) {
                const int col = (int)brow0 + wn * 32 + tn * 16 + l16;
                const float bkc = bwk[col];
                const float bvc = bwv[col];
#pragma unroll
                for (int r = 0; r < 4; ++r) {
                    const float kp = fmaxf(acck[tm][tn][r] + bkc, 0.f);
                    const float vp = accv[tm][tn][r] + bvc;
                    const __bf16 kb = (__bf16)(kp * vp);
                    __builtin_nontemporal_store(kb, &kvb[(row0 + r) * D + col]);
                    part[tn][tm >> 1] += (float)kb;
                }
            }
        }
        // reduce over quads (rows within the 32-row chunk) and store Csum
#pragma unroll
        for (int tn = 0; tn < 2; ++tn)
#pragma unroll
            for (int th = 0; th < 2; ++th) {
                float vv = part[tn][th];
                vv += __shfl_xor(vv, 16, 64);
                vv += __shfl_xor(vv, 32, 64);
                if (quad == 0) {
                    const int fc = ((int)(arow0 >> 5)) + wm * 2 + th; // flat chunk
                    const int bb = fc / NCH;
                    const int cc = fc - bb * NCH;
                    const int col = (int)brow0 + wn * 32 + tn * 16 + l16;
                    Csum[((long)bb * NCH + cc) * D + col] = vv;
                }
            }
    }
}

// ---------------------------------------------------------------------------
// Kernel 3: sliding window (1024) via chunk-sum init + rolling edges,
// times relu(qp).  TI=32 query rows/block, 2 cols/thread.
// ---------------------------------------------------------------------------
__global__ __launch_bounds__(256) void window_kernel(
    const __bf16* __restrict__ kv, const float* __restrict__ Csum,
    const __bf16* __restrict__ qpb, float* __restrict__ out)
{
    const int iq   = blockIdx.x;        // 0..127
    const int b    = blockIdx.y;
    const int i0   = iq * TI;
    const int col2 = threadIdx.x * 2;

    const float* cs = Csum + (long)b * NCH * D + col2;
    float s0 = 0.f, s1 = 0.f;
#pragma unroll
    for (int c = 0; c < 32; ++c) {
        const float2 cv = *reinterpret_cast<const float2*>(cs + (long)(iq + c) * D);
        s0 += cv.x; s1 += cv.y;
    }

    const __bf16* kvb = kv  + (long)b * LKP * D + col2;
    const __bf16* qb  = qpb + (long)b * LQ  * D + col2;
    float*        ob  = out + (long)b * LQ  * D + col2;

#pragma unroll 8
    for (int i = i0; i < i0 + TI; ++i) {
        const bf16x2 qv = *reinterpret_cast<const bf16x2*>(qb + (long)i * D);
        *reinterpret_cast<float2*>(ob + (long)i * D) =
            make_float2((float)qv[0] * s0, (float)qv[1] * s1);
        const bf16x2 lead  = *reinterpret_cast<const bf16x2*>(kvb + (long)(i + CACHE) * D);
        const bf16x2 trail = *reinterpret_cast<const bf16x2*>(kvb + (long)i * D);
        s0 += (float)lead[0] - (float)trail[0];
        s1 += (float)lead[1] - (float)trail[1];
    }
}

// ---------------------------------------------------------------------------
extern "C" void kernel_launch(void* const* d_in, const int* in_sizes, int n_in,
                              void* d_out, int out_size, void* d_ws, size_t ws_size,
                              hipStream_t stream)
{
    const float* q   = (const float*)d_in[0];
    const float* k   = (const float*)d_in[1];
    const float* v   = (const float*)d_in[2];
    const float* gq  = (const float*)d_in[3];
    const float* bq  = (const float*)d_in[4];
    const float* gk  = (const float*)d_in[5];
    const float* bk  = (const float*)d_in[6];
    const float* gv  = (const float*)d_in[7];
    const float* bv  = (const float*)d_in[8];
    const float* Wq  = (const float*)d_in[9];
    const float* bwq = (const float*)d_in[10];
    const float* Wk  = (const float*)d_in[11];
    const float* bwk = (const float*)d_in[12];
    const float* Wv  = (const float*)d_in[13];
    const float* bwv = (const float*)d_in[14];
    float* out = (float*)d_out;

    // Workspace layout (k/v-side tensors per-batch padded: stride LKP rows)
    char* ws = (char*)d_ws;
    __bf16* qn   = (__bf16*)ws;                      // [MQ ][D] bf16
    __bf16* kn   = qn  + (long)MQ  * D;              // [MKP][D] bf16 (padded)
    __bf16* vn   = kn  + (long)MKP * D;              // [MKP][D] bf16 (padded)
    __bf16* qpb  = vn  + (long)MKP * D;              // [MQ ][D] bf16  relu(qp)
    __bf16* kvb  = qpb + (long)MQ  * D;              // [MKP][D] bf16 (padded)
    __bf16* wtq  = kvb + (long)MKP * D;              // [D][D] bf16 transposed
    __bf16* wtk  = wtq + (long)D * D;
    __bf16* wtv  = wtk + (long)D * D;
    float*  Csum = (float*)(wtv + (long)D * D);      // [B][NCH][D] f32

    // 1) LN(q,k,v) + weight transpose in ONE dispatch
    prep_kernel<<<dim3(2560, 4), 256, 0, stream>>>(
        q, k, v, gq, bq, gk, bk, gv, bv, Wq, Wk, Wv,
        qn, kn, vn, wtq, wtk, wtv);

    // 2) qp-GEMM + kv-dual-GEMM (+ fused chunk sums) in ONE dispatch
    gemm_fused_kernel<<<512 + 1280, 256, 0, stream>>>(
        qn, kn, vn, wtq, wtk, wtv, bwq, bwk, bwv, qpb, kvb, Csum);

    // 3) window sum x relu(qp)
    window_kernel<<<dim3(LQ / TI, B), 256, 0, stream>>>(kvb, Csum, qpb, out);
}

// Round 8
// 249.725 us; speedup vs baseline: 1.0940x; 1.0940x over previous
//
#include <hip/hip_runtime.h>

// Problem constants
#define B     4
#define LQ    4096
#define LK    5119
#define LKP   5120              // per-batch padded rows (160 chunks of 32)
#define D     512
#define CACHE 1024
#define MQ    (B * LQ)          // 16384 = 128*128
#define MKP   (B * LKP)         // 20480 = 160*128
#define NCH   160               // 32-row chunks per batch
#define TI    32                // query rows per window block

typedef float  f32x4  __attribute__((ext_vector_type(4)));
typedef __bf16 bf16x2 __attribute__((ext_vector_type(2)));
typedef __bf16 bf16x8 __attribute__((ext_vector_type(8)));

// async global->LDS, 16B per lane; lds base wave-uniform (HW adds lane*16)
__device__ __forceinline__ void async16(void* lds, const void* g)
{
    __builtin_amdgcn_global_load_lds(
        (__attribute__((address_space(1))) void*)(g),
        (__attribute__((address_space(3))) void*)(lds),
        16, 0, 0);
}

// ---------------------------------------------------------------------------
// Kernel 1 (prep): z in {0,1,2}: LayerNorm -> bf16 (half-wave per row,
// 8 rows/block).  k/v outputs use per-batch-padded layout (stride LKP rows,
// row 5119 of each batch left unwritten).  z == 3: weight transpose f32->bf16.
// NOTE (R7 lesson): plain stores only — nt-stores bypass L3 and force the
// consumer GEMM to re-read everything from HBM (FETCH 109->199 MB).
// ---------------------------------------------------------------------------
__global__ __launch_bounds__(256) void prep_kernel(
    const float* __restrict__ q, const float* __restrict__ k,
    const float* __restrict__ v,
    const float* __restrict__ gq, const float* __restrict__ bq,
    const float* __restrict__ gk, const float* __restrict__ bk,
    const float* __restrict__ gv, const float* __restrict__ bv,
    const float* __restrict__ Wq, const float* __restrict__ Wk,
    const float* __restrict__ Wv,
    __bf16* __restrict__ qn, __bf16* __restrict__ kn, __bf16* __restrict__ vn,
    __bf16* __restrict__ wtq, __bf16* __restrict__ wtk, __bf16* __restrict__ wtv)
{
    const int z = blockIdx.y;

    if (z == 3) {               // ---- weight transpose-convert ----
        const int idx = blockIdx.x;
        if (idx >= 384) return;
        const int zz  = idx >> 7;        // 0..2
        const int rem = idx & 127;
        const float* W = (zz == 0) ? Wq : (zz == 1) ? Wk : Wv;
        __bf16*     Wt = (zz == 0) ? wtq : (zz == 1) ? wtk : wtv;
        const int n  = (rem & 1) * 256 + threadIdx.x;
        const int k0 = (rem >> 1) * 8;
        bf16x8 o;
#pragma unroll
        for (int j = 0; j < 8; ++j)
            o[j] = (__bf16)W[(long)(k0 + j) * D + n];
        *reinterpret_cast<bf16x8*>(Wt + (long)n * D + k0) = o;
        return;
    }

    // ---- LayerNorm ----
    const float *x, *g, *bb; __bf16* o;
    if (z == 0)      { x = q; g = gq; bb = bq; o = qn; }
    else if (z == 1) { x = k; g = gk; bb = bk; o = kn; }
    else             { x = v; g = gv; bb = bv; o = vn; }

    const int rp = blockIdx.x * 8 + (threadIdx.x >> 5);   // padded row id
    long rin;
    if (z == 0) {
        if (rp >= MQ) return;
        rin = rp;
    } else {
        const int bch = rp / LKP;
        const int i   = rp - bch * LKP;
        if (i == LK) return;            // per-batch pad row, leave garbage
        rin = (long)bch * LK + i;
    }

    const int c0 = (threadIdx.x & 31) * 16;
    const float* xr = x + rin * D + c0;

    float4 a[4];
#pragma unroll
    for (int j = 0; j < 4; ++j)
        a[j] = *reinterpret_cast<const float4*>(xr + j * 4);

    float s = 0.f, ss = 0.f;
#pragma unroll
    for (int j = 0; j < 4; ++j) {
        s  += a[j].x + a[j].y + a[j].z + a[j].w;
        ss += a[j].x*a[j].x + a[j].y*a[j].y + a[j].z*a[j].z + a[j].w*a[j].w;
    }
#pragma unroll
    for (int m = 1; m <= 16; m <<= 1) {     // reduce within 32-lane half
        s  += __shfl_xor(s,  m, 64);
        ss += __shfl_xor(ss, m, 64);
    }
    const float mean = s * (1.f / (float)D);
    const float var  = ss * (1.f / (float)D) - mean * mean;
    const float rs   = rsqrtf(var + 1e-5f);

    bf16x8 o0, o1;
#pragma unroll
    for (int j = 0; j < 4; ++j) {
        const float4 gv4 = *reinterpret_cast<const float4*>(g  + c0 + j * 4);
        const float4 bv4 = *reinterpret_cast<const float4*>(bb + c0 + j * 4);
        const float y0 = (a[j].x - mean) * rs * gv4.x + bv4.x;
        const float y1 = (a[j].y - mean) * rs * gv4.y + bv4.y;
        const float y2 = (a[j].z - mean) * rs * gv4.z + bv4.z;
        const float y3 = (a[j].w - mean) * rs * gv4.w + bv4.w;
        if (j < 2) {
            o0[j*4+0] = (__bf16)y0; o0[j*4+1] = (__bf16)y1;
            o0[j*4+2] = (__bf16)y2; o0[j*4+3] = (__bf16)y3;
        } else {
            o1[(j-2)*4+0] = (__bf16)y0; o1[(j-2)*4+1] = (__bf16)y1;
            o1[(j-2)*4+2] = (__bf16)y2; o1[(j-2)*4+3] = (__bf16)y3;
        }
    }
    __bf16* orow = o + (long)rp * D + c0;
    *reinterpret_cast<bf16x8*>(orow)     = o0;
    *reinterpret_cast<bf16x8*>(orow + 8) = o1;
}

// ---------------------------------------------------------------------------
// Kernel 2 (gemm_fused): bid < 512 -> qp = relu(qn@Wq + bwq) (128x128 tile);
// bid >= 512 -> kv = relu(kn@Wk + bwk) * (vn@Wv + bwv) (128x64 tile) with
// fused 32-row chunk sums stored to Csum.  Both paths use ntile-INNER block
// order so consecutive blocks share the same A-tile (L2/L3 locality).
// BK=64, async16 staging, XOR-swizzled 16B chunks (conflict-free).
// ---------------------------------------------------------------------------
__global__ __launch_bounds__(256, 2) void gemm_fused_kernel(
    const __bf16* __restrict__ qn, const __bf16* __restrict__ kn,
    const __bf16* __restrict__ vn,
    const __bf16* __restrict__ wtq, const __bf16* __restrict__ wtk,
    const __bf16* __restrict__ wtv,
    const float* __restrict__ bwq, const float* __restrict__ bwk,
    const float* __restrict__ bwv,
    __bf16* __restrict__ qpb, __bf16* __restrict__ kvb,
    float* __restrict__ Csum)
{
    __shared__ __attribute__((aligned(16))) __bf16 smem[24576];  // 48 KB

    const int bid  = blockIdx.x;
    const int tid  = threadIdx.x;
    const int lane = tid & 63;
    const int wave = tid >> 6;
    const int quad = lane >> 4;
    const int l16  = lane & 15;
    const int wm   = wave >> 1;
    const int wn   = wave & 1;
    const int lrow = lane >> 3;                    // 0..7
    const int lcs  = ((lane & 7) ^ lrow) * 8;      // swizzled k-col (bf16)

    if (bid < 512) {
        // ================= q GEMM: 128x128 tile =================
        __bf16* As = smem;                // 128*64
        __bf16* Bs = smem + 8192;         // 128*64

        f32x4 acc[4][4];
#pragma unroll
        for (int i = 0; i < 4; ++i)
#pragma unroll
            for (int j = 0; j < 4; ++j)
                acc[i][j] = (f32x4){0.f, 0.f, 0.f, 0.f};

        const long arow0 = (long)(bid >> 2) * 128;
        const long brow0 = (long)(bid & 3) * 128;

        for (int k0 = 0; k0 < D; k0 += 64) {
#pragma unroll
            for (int j = 0; j < 4; ++j) {
                const int r0  = (j * 4 + wave) * 8;
                const int row = r0 + lrow;
                async16(&As[r0 * 64], &qn [(arow0 + row) * D + k0 + lcs]);
                async16(&Bs[r0 * 64], &wtq[(brow0 + row) * D + k0 + lcs]);
            }
            __syncthreads();

            bf16x8 af[4][2], bf[4][2];
#pragma unroll
            for (int tm = 0; tm < 4; ++tm) {
                const int m = wm * 64 + tm * 16 + l16;
#pragma unroll
                for (int kh = 0; kh < 2; ++kh)
                    af[tm][kh] = *reinterpret_cast<const bf16x8*>(
                        &As[m * 64 + (((kh * 4 + quad) ^ (m & 7)) * 8)]);
            }
#pragma unroll
            for (int tn = 0; tn < 4; ++tn) {
                const int n = wn * 64 + tn * 16 + l16;
#pragma unroll
                for (int kh = 0; kh < 2; ++kh)
                    bf[tn][kh] = *reinterpret_cast<const bf16x8*>(
                        &Bs[n * 64 + (((kh * 4 + quad) ^ (n & 7)) * 8)]);
            }
#pragma unroll
            for (int kh = 0; kh < 2; ++kh)
#pragma unroll
                for (int tm = 0; tm < 4; ++tm)
#pragma unroll
                    for (int tn = 0; tn < 4; ++tn)
                        acc[tm][tn] = __builtin_amdgcn_mfma_f32_16x16x32_bf16(
                            af[tm][kh], bf[tn][kh], acc[tm][tn], 0, 0, 0);
            __syncthreads();
        }

#pragma unroll
        for (int tm = 0; tm < 4; ++tm) {
            const long row0 = arow0 + wm * 64 + tm * 16 + quad * 4;
#pragma unroll
            for (int tn = 0; tn < 4; ++tn) {
                const int col = (int)brow0 + wn * 64 + tn * 16 + l16;
                const float bv = bwq[col];
#pragma unroll
                for (int r = 0; r < 4; ++r)
                    qpb[(row0 + r) * D + col] =
                        (__bf16)fmaxf(acc[tm][tn][r] + bv, 0.f);
            }
        }
    } else {
        // ================= kv dual GEMM: 128x64 tile =================
        __bf16* Ks  = smem;               // 128*64
        __bf16* Vs  = smem + 8192;        // 128*64
        __bf16* WKs = smem + 16384;       // 64*64
        __bf16* WVs = smem + 20480;       // 64*64

        const int bid2  = bid - 512;
        const int mtile = bid2 >> 3;      // ntile-inner: 8 consecutive blocks
        const int ntile = bid2 & 7;       // share one 128-row A-tile

        f32x4 acck[4][2], accv[4][2];
#pragma unroll
        for (int i = 0; i < 4; ++i)
#pragma unroll
            for (int j = 0; j < 2; ++j) {
                acck[i][j] = (f32x4){0.f, 0.f, 0.f, 0.f};
                accv[i][j] = (f32x4){0.f, 0.f, 0.f, 0.f};
            }

        const long arow0 = (long)mtile * 128;
        const long brow0 = (long)ntile * 64;

        for (int k0 = 0; k0 < D; k0 += 64) {
#pragma unroll
            for (int j = 0; j < 4; ++j) {
                const int r0  = (j * 4 + wave) * 8;
                const int row = r0 + lrow;
                async16(&Ks[r0 * 64], &kn[(arow0 + row) * D + k0 + lcs]);
                async16(&Vs[r0 * 64], &vn[(arow0 + row) * D + k0 + lcs]);
            }
#pragma unroll
            for (int j = 0; j < 2; ++j) {
                const int r0  = (j * 4 + wave) * 8;
                const int row = r0 + lrow;
                async16(&WKs[r0 * 64], &wtk[(brow0 + row) * D + k0 + lcs]);
                async16(&WVs[r0 * 64], &wtv[(brow0 + row) * D + k0 + lcs]);
            }
            __syncthreads();

            bf16x8 fa[4][2], fb[2][2];
#pragma unroll
            for (int tm = 0; tm < 4; ++tm) {
                const int m = wm * 64 + tm * 16 + l16;
#pragma unroll
                for (int kh = 0; kh < 2; ++kh)
                    fa[tm][kh] = *reinterpret_cast<const bf16x8*>(
                        &Ks[m * 64 + (((kh * 4 + quad) ^ (m & 7)) * 8)]);
            }
#pragma unroll
            for (int tn = 0; tn < 2; ++tn) {
                const int n = wn * 32 + tn * 16 + l16;
#pragma unroll
                for (int kh = 0; kh < 2; ++kh)
                    fb[tn][kh] = *reinterpret_cast<const bf16x8*>(
                        &WKs[n * 64 + (((kh * 4 + quad) ^ (n & 7)) * 8)]);
            }
#pragma unroll
            for (int kh = 0; kh < 2; ++kh)
#pragma unroll
                for (int tm = 0; tm < 4; ++tm)
#pragma unroll
                    for (int tn = 0; tn < 2; ++tn)
                        acck[tm][tn] = __builtin_amdgcn_mfma_f32_16x16x32_bf16(
                            fa[tm][kh], fb[tn][kh], acck[tm][tn], 0, 0, 0);
#pragma unroll
            for (int tm = 0; tm < 4; ++tm) {
                const int m = wm * 64 + tm * 16 + l16;
#pragma unroll
                for (int kh = 0; kh < 2; ++kh)
                    fa[tm][kh] = *reinterpret_cast<const bf16x8*>(
                        &Vs[m * 64 + (((kh * 4 + quad) ^ (m & 7)) * 8)]);
            }
#pragma unroll
            for (int tn = 0; tn < 2; ++tn) {
                const int n = wn * 32 + tn * 16 + l16;
#pragma unroll
                for (int kh = 0; kh < 2; ++kh)
                    fb[tn][kh] = *reinterpret_cast<const bf16x8*>(
                        &WVs[n * 64 + (((kh * 4 + quad) ^ (n & 7)) * 8)]);
            }
#pragma unroll
            for (int kh = 0; kh < 2; ++kh)
#pragma unroll
                for (int tm = 0; tm < 4; ++tm)
#pragma unroll
                    for (int tn = 0; tn < 2; ++tn)
                        accv[tm][tn] = __builtin_amdgcn_mfma_f32_16x16x32_bf16(
                            fa[tm][kh], fb[tn][kh], accv[tm][tn], 0, 0, 0);
            __syncthreads();
        }

        // epilogue: write kv (bf16) and accumulate 32-row chunk partials
        float part[2][2] = {{0.f, 0.f}, {0.f, 0.f}};   // [tn][tm>>1]
#pragma unroll
        for (int tm = 0; tm < 4; ++tm) {
            const long row0 = arow0 + wm * 64 + tm * 16 + quad * 4;
#pragma unroll
            for (int tn = 0; tn < 2; ++tn) {
                const int col = (int)brow0 + wn * 32 + tn * 16 + l16;
                const float bkc = bwk[col];
                const float bvc = bwv[col];
#pragma unroll
                for (int r = 0; r < 4; ++r) {
                    const float kp = fmaxf(acck[tm][tn][r] + bkc, 0.f);
                    const float vp = accv[tm][tn][r] + bvc;
                    const __bf16 kb = (__bf16)(kp * vp);
                    kvb[(row0 + r) * D + col] = kb;
                    part[tn][tm >> 1] += (float)kb;
                }
            }
        }
        // reduce over quads (rows within the 32-row chunk) and store Csum
#pragma unroll
        for (int tn = 0; tn < 2; ++tn)
#pragma unroll
            for (int th = 0; th < 2; ++th) {
                float vv = part[tn][th];
                vv += __shfl_xor(vv, 16, 64);
                vv += __shfl_xor(vv, 32, 64);
                if (quad == 0) {
                    const int fc = ((int)(arow0 >> 5)) + wm * 2 + th; // flat chunk
                    const int bb = fc / NCH;
                    const int cc = fc - bb * NCH;
                    const int col = (int)brow0 + wn * 32 + tn * 16 + l16;
                    Csum[((long)bb * NCH + cc) * D + col] = vv;
                }
            }
    }
}

// ---------------------------------------------------------------------------
// Kernel 3: sliding window (1024) via chunk-sum init + rolling edges,
// times relu(qp).  TI=32 query rows/block, 2 cols/thread.
// ---------------------------------------------------------------------------
__global__ __launch_bounds__(256) void window_kernel(
    const __bf16* __restrict__ kv, const float* __restrict__ Csum,
    const __bf16* __restrict__ qpb, float* __restrict__ out)
{
    const int iq   = blockIdx.x;        // 0..127
    const int b    = blockIdx.y;
    const int i0   = iq * TI;
    const int col2 = threadIdx.x * 2;

    const float* cs = Csum + (long)b * NCH * D + col2;
    float s0 = 0.f, s1 = 0.f;
#pragma unroll
    for (int c = 0; c < 32; ++c) {
        const float2 cv = *reinterpret_cast<const float2*>(cs + (long)(iq + c) * D);
        s0 += cv.x; s1 += cv.y;
    }

    const __bf16* kvb = kv  + (long)b * LKP * D + col2;
    const __bf16* qb  = qpb + (long)b * LQ  * D + col2;
    float*        ob  = out + (long)b * LQ  * D + col2;

#pragma unroll 8
    for (int i = i0; i < i0 + TI; ++i) {
        const bf16x2 qv = *reinterpret_cast<const bf16x2*>(qb + (long)i * D);
        *reinterpret_cast<float2*>(ob + (long)i * D) =
            make_float2((float)qv[0] * s0, (float)qv[1] * s1);
        const bf16x2 lead  = *reinterpret_cast<const bf16x2*>(kvb + (long)(i + CACHE) * D);
        const bf16x2 trail = *reinterpret_cast<const bf16x2*>(kvb + (long)i * D);
        s0 += (float)lead[0] - (float)trail[0];
        s1 += (float)lead[1] - (float)trail[1];
    }
}

// ---------------------------------------------------------------------------
extern "C" void kernel_launch(void* const* d_in, const int* in_sizes, int n_in,
                              void* d_out, int out_size, void* d_ws, size_t ws_size,
                              hipStream_t stream)
{
    const float* q   = (const float*)d_in[0];
    const float* k   = (const float*)d_in[1];
    const float* v   = (const float*)d_in[2];
    const float* gq  = (const float*)d_in[3];
    const float* bq  = (const float*)d_in[4];
    const float* gk  = (const float*)d_in[5];
    const float* bk  = (const float*)d_in[6];
    const float* gv  = (const float*)d_in[7];
    const float* bv  = (const float*)d_in[8];
    const float* Wq  = (const float*)d_in[9];
    const float* bwq = (const float*)d_in[10];
    const float* Wk  = (const float*)d_in[11];
    const float* bwk = (const float*)d_in[12];
    const float* Wv  = (const float*)d_in[13];
    const float* bwv = (const float*)d_in[14];
    float* out = (float*)d_out;

    // Workspace layout (k/v-side tensors per-batch padded: stride LKP rows)
    char* ws = (char*)d_ws;
    __bf16* qn   = (__bf16*)ws;                      // [MQ ][D] bf16
    __bf16* kn   = qn  + (long)MQ  * D;              // [MKP][D] bf16 (padded)
    __bf16* vn   = kn  + (long)MKP * D;              // [MKP][D] bf16 (padded)
    __bf16* qpb  = vn  + (long)MKP * D;              // [MQ ][D] bf16  relu(qp)
    __bf16* kvb  = qpb + (long)MQ  * D;              // [MKP][D] bf16 (padded)
    __bf16* wtq  = kvb + (long)MKP * D;              // [D][D] bf16 transposed
    __bf16* wtk  = wtq + (long)D * D;
    __bf16* wtv  = wtk + (long)D * D;
    float*  Csum = (float*)(wtv + (long)D * D);      // [B][NCH][D] f32

    // 1) LN(q,k,v) + weight transpose in ONE dispatch
    prep_kernel<<<dim3(2560, 4), 256, 0, stream>>>(
        q, k, v, gq, bq, gk, bk, gv, bv, Wq, Wk, Wv,
        qn, kn, vn, wtq, wtk, wtv);

    // 2) qp-GEMM + kv-dual-GEMM (+ fused chunk sums) in ONE dispatch
    gemm_fused_kernel<<<512 + 1280, 256, 0, stream>>>(
        qn, kn, vn, wtq, wtk, wtv, bwq, bwk, bwv, qpb, kvb, Csum);

    // 3) window sum x relu(qp)
    window_kernel<<<dim3(LQ / TI, B), 256, 0, stream>>>(kvb, Csum, qpb, out);
}

// Round 9
// 233.420 us; speedup vs baseline: 1.1704x; 1.0699x over previous
//
#include <hip/hip_runtime.h>

// Problem constants
#define B     4
#define LQ    4096
#define LK    5119
#define LKP   5120              // per-batch padded rows (160 chunks of 32)
#define D     512
#define CACHE 1024
#define MQ    (B * LQ)          // 16384 = 128*128
#define MKP   (B * LKP)         // 20480 = 160*128
#define NCH   160               // 32-row chunks per batch
#define TI    32                // query rows per window block

typedef float  f32x4  __attribute__((ext_vector_type(4)));
typedef __bf16 bf16x2 __attribute__((ext_vector_type(2)));
typedef __bf16 bf16x8 __attribute__((ext_vector_type(8)));

// async global->LDS, 16B per lane; lds base wave-uniform (HW adds lane*16)
__device__ __forceinline__ void async16(void* lds, const void* g)
{
    __builtin_amdgcn_global_load_lds(
        (__attribute__((address_space(1))) void*)(g),
        (__attribute__((address_space(3))) void*)(lds),
        16, 0, 0);
}

// ---------------------------------------------------------------------------
// Kernel 1 (prep): z in {0,1,2}: LayerNorm -> bf16 (half-wave per row,
// 8 rows/block).  k/v outputs use per-batch-padded layout (stride LKP rows,
// row 5119 of each batch left unwritten).  z == 3: weight transpose f32->bf16.
// NOTE (R7 lesson): plain stores only — nt-stores bypass L3 and force the
// consumer GEMM to re-read everything from HBM.
// ---------------------------------------------------------------------------
__global__ __launch_bounds__(256) void prep_kernel(
    const float* __restrict__ q, const float* __restrict__ k,
    const float* __restrict__ v,
    const float* __restrict__ gq, const float* __restrict__ bq,
    const float* __restrict__ gk, const float* __restrict__ bk,
    const float* __restrict__ gv, const float* __restrict__ bv,
    const float* __restrict__ Wq, const float* __restrict__ Wk,
    const float* __restrict__ Wv,
    __bf16* __restrict__ qn, __bf16* __restrict__ kn, __bf16* __restrict__ vn,
    __bf16* __restrict__ wtq, __bf16* __restrict__ wtk, __bf16* __restrict__ wtv)
{
    const int z = blockIdx.y;

    if (z == 3) {               // ---- weight transpose-convert ----
        const int idx = blockIdx.x;
        if (idx >= 384) return;
        const int zz  = idx >> 7;        // 0..2
        const int rem = idx & 127;
        const float* W = (zz == 0) ? Wq : (zz == 1) ? Wk : Wv;
        __bf16*     Wt = (zz == 0) ? wtq : (zz == 1) ? wtk : wtv;
        const int n  = (rem & 1) * 256 + threadIdx.x;
        const int k0 = (rem >> 1) * 8;
        bf16x8 o;
#pragma unroll
        for (int j = 0; j < 8; ++j)
            o[j] = (__bf16)W[(long)(k0 + j) * D + n];
        *reinterpret_cast<bf16x8*>(Wt + (long)n * D + k0) = o;
        return;
    }

    // ---- LayerNorm ----
    const float *x, *g, *bb; __bf16* o;
    if (z == 0)      { x = q; g = gq; bb = bq; o = qn; }
    else if (z == 1) { x = k; g = gk; bb = bk; o = kn; }
    else             { x = v; g = gv; bb = bv; o = vn; }

    const int rp = blockIdx.x * 8 + (threadIdx.x >> 5);   // padded row id
    long rin;
    if (z == 0) {
        if (rp >= MQ) return;
        rin = rp;
    } else {
        const int bch = rp / LKP;
        const int i   = rp - bch * LKP;
        if (i == LK) return;            // per-batch pad row, leave garbage
        rin = (long)bch * LK + i;
    }

    const int c0 = (threadIdx.x & 31) * 16;
    const float* xr = x + rin * D + c0;

    float4 a[4];
#pragma unroll
    for (int j = 0; j < 4; ++j)
        a[j] = *reinterpret_cast<const float4*>(xr + j * 4);

    float s = 0.f, ss = 0.f;
#pragma unroll
    for (int j = 0; j < 4; ++j) {
        s  += a[j].x + a[j].y + a[j].z + a[j].w;
        ss += a[j].x*a[j].x + a[j].y*a[j].y + a[j].z*a[j].z + a[j].w*a[j].w;
    }
#pragma unroll
    for (int m = 1; m <= 16; m <<= 1) {     // reduce within 32-lane half
        s  += __shfl_xor(s,  m, 64);
        ss += __shfl_xor(ss, m, 64);
    }
    const float mean = s * (1.f / (float)D);
    const float var  = ss * (1.f / (float)D) - mean * mean;
    const float rs   = rsqrtf(var + 1e-5f);

    bf16x8 o0, o1;
#pragma unroll
    for (int j = 0; j < 4; ++j) {
        const float4 gv4 = *reinterpret_cast<const float4*>(g  + c0 + j * 4);
        const float4 bv4 = *reinterpret_cast<const float4*>(bb + c0 + j * 4);
        const float y0 = (a[j].x - mean) * rs * gv4.x + bv4.x;
        const float y1 = (a[j].y - mean) * rs * gv4.y + bv4.y;
        const float y2 = (a[j].z - mean) * rs * gv4.z + bv4.z;
        const float y3 = (a[j].w - mean) * rs * gv4.w + bv4.w;
        if (j < 2) {
            o0[j*4+0] = (__bf16)y0; o0[j*4+1] = (__bf16)y1;
            o0[j*4+2] = (__bf16)y2; o0[j*4+3] = (__bf16)y3;
        } else {
            o1[(j-2)*4+0] = (__bf16)y0; o1[(j-2)*4+1] = (__bf16)y1;
            o1[(j-2)*4+2] = (__bf16)y2; o1[(j-2)*4+3] = (__bf16)y3;
        }
    }
    __bf16* orow = o + (long)rp * D + c0;
    *reinterpret_cast<bf16x8*>(orow)     = o0;
    *reinterpret_cast<bf16x8*>(orow + 8) = o1;
}

// ---------------------------------------------------------------------------
// Kernel 2 (gemm_fused): bid < 512 -> qp = relu(qn@Wq + bwq) (128x128 tile);
// bid >= 512 -> kv = relu(kn@Wk + bwk) * (vn@Wv + bwv) (128x64 tile) with
// fused 32-row chunk sums stored to Csum.
// Block order: mtile-INNER on both paths.  Blocks go to XCD (bid % 8) and
// the mtile period (128 and 160) is ≡0 mod 8, so every block touching A-tile
// m lands on XCD m%8 -> the A stream is fetched once per L2 and reused
// across all ntile passes (R8 post-mortem: ntile-inner scattered each A-tile
// over all 8 XCD L2s -> FETCH 199 MB vs 109 MB).
// BK=64, async16 staging, XOR-swizzled 16B chunks (conflict-free).
// ---------------------------------------------------------------------------
__global__ __launch_bounds__(256, 2) void gemm_fused_kernel(
    const __bf16* __restrict__ qn, const __bf16* __restrict__ kn,
    const __bf16* __restrict__ vn,
    const __bf16* __restrict__ wtq, const __bf16* __restrict__ wtk,
    const __bf16* __restrict__ wtv,
    const float* __restrict__ bwq, const float* __restrict__ bwk,
    const float* __restrict__ bwv,
    __bf16* __restrict__ qpb, __bf16* __restrict__ kvb,
    float* __restrict__ Csum)
{
    __shared__ __attribute__((aligned(16))) __bf16 smem[24576];  // 48 KB

    const int bid  = blockIdx.x;
    const int tid  = threadIdx.x;
    const int lane = tid & 63;
    const int wave = tid >> 6;
    const int quad = lane >> 4;
    const int l16  = lane & 15;
    const int wm   = wave >> 1;
    const int wn   = wave & 1;
    const int lrow = lane >> 3;                    // 0..7
    const int lcs  = ((lane & 7) ^ lrow) * 8;      // swizzled k-col (bf16)

    if (bid < 512) {
        // ================= q GEMM: 128x128 tile =================
        __bf16* As = smem;                // 128*64
        __bf16* Bs = smem + 8192;         // 128*64

        f32x4 acc[4][4];
#pragma unroll
        for (int i = 0; i < 4; ++i)
#pragma unroll
            for (int j = 0; j < 4; ++j)
                acc[i][j] = (f32x4){0.f, 0.f, 0.f, 0.f};

        const long arow0 = (long)(bid & 127) * 128;   // mtile-inner
        const long brow0 = (long)(bid >> 7) * 128;    // 4 ntile passes

        for (int k0 = 0; k0 < D; k0 += 64) {
#pragma unroll
            for (int j = 0; j < 4; ++j) {
                const int r0  = (j * 4 + wave) * 8;
                const int row = r0 + lrow;
                async16(&As[r0 * 64], &qn [(arow0 + row) * D + k0 + lcs]);
                async16(&Bs[r0 * 64], &wtq[(brow0 + row) * D + k0 + lcs]);
            }
            __syncthreads();

            bf16x8 af[4][2], bf[4][2];
#pragma unroll
            for (int tm = 0; tm < 4; ++tm) {
                const int m = wm * 64 + tm * 16 + l16;
#pragma unroll
                for (int kh = 0; kh < 2; ++kh)
                    af[tm][kh] = *reinterpret_cast<const bf16x8*>(
                        &As[m * 64 + (((kh * 4 + quad) ^ (m & 7)) * 8)]);
            }
#pragma unroll
            for (int tn = 0; tn < 4; ++tn) {
                const int n = wn * 64 + tn * 16 + l16;
#pragma unroll
                for (int kh = 0; kh < 2; ++kh)
                    bf[tn][kh] = *reinterpret_cast<const bf16x8*>(
                        &Bs[n * 64 + (((kh * 4 + quad) ^ (n & 7)) * 8)]);
            }
#pragma unroll
            for (int kh = 0; kh < 2; ++kh)
#pragma unroll
                for (int tm = 0; tm < 4; ++tm)
#pragma unroll
                    for (int tn = 0; tn < 4; ++tn)
                        acc[tm][tn] = __builtin_amdgcn_mfma_f32_16x16x32_bf16(
                            af[tm][kh], bf[tn][kh], acc[tm][tn], 0, 0, 0);
            __syncthreads();
        }

#pragma unroll
        for (int tm = 0; tm < 4; ++tm) {
            const long row0 = arow0 + wm * 64 + tm * 16 + quad * 4;
#pragma unroll
            for (int tn = 0; tn < 4; ++tn) {
                const int col = (int)brow0 + wn * 64 + tn * 16 + l16;
                const float bv = bwq[col];
#pragma unroll
                for (int r = 0; r < 4; ++r)
                    qpb[(row0 + r) * D + col] =
                        (__bf16)fmaxf(acc[tm][tn][r] + bv, 0.f);
            }
        }
    } else {
        // ================= kv dual GEMM: 128x64 tile =================
        __bf16* Ks  = smem;               // 128*64
        __bf16* Vs  = smem + 8192;        // 128*64
        __bf16* WKs = smem + 16384;       // 64*64
        __bf16* WVs = smem + 20480;       // 64*64

        const int bid2  = bid - 512;
        const int ntile = bid2 / 160;     // mtile-inner (XCD affinity: 160%8==0)
        const int mtile = bid2 - ntile * 160;

        f32x4 acck[4][2], accv[4][2];
#pragma unroll
        for (int i = 0; i < 4; ++i)
#pragma unroll
            for (int j = 0; j < 2; ++j) {
                acck[i][j] = (f32x4){0.f, 0.f, 0.f, 0.f};
                accv[i][j] = (f32x4){0.f, 0.f, 0.f, 0.f};
            }

        const long arow0 = (long)mtile * 128;
        const long brow0 = (long)ntile * 64;

        for (int k0 = 0; k0 < D; k0 += 64) {
#pragma unroll
            for (int j = 0; j < 4; ++j) {
                const int r0  = (j * 4 + wave) * 8;
                const int row = r0 + lrow;
                async16(&Ks[r0 * 64], &kn[(arow0 + row) * D + k0 + lcs]);
                async16(&Vs[r0 * 64], &vn[(arow0 + row) * D + k0 + lcs]);
            }
#pragma unroll
            for (int j = 0; j < 2; ++j) {
                const int r0  = (j * 4 + wave) * 8;
                const int row = r0 + lrow;
                async16(&WKs[r0 * 64], &wtk[(brow0 + row) * D + k0 + lcs]);
                async16(&WVs[r0 * 64], &wtv[(brow0 + row) * D + k0 + lcs]);
            }
            __syncthreads();

            bf16x8 fa[4][2], fb[2][2];
#pragma unroll
            for (int tm = 0; tm < 4; ++tm) {
                const int m = wm * 64 + tm * 16 + l16;
#pragma unroll
                for (int kh = 0; kh < 2; ++kh)
                    fa[tm][kh] = *reinterpret_cast<const bf16x8*>(
                        &Ks[m * 64 + (((kh * 4 + quad) ^ (m & 7)) * 8)]);
            }
#pragma unroll
            for (int tn = 0; tn < 2; ++tn) {
                const int n = wn * 32 + tn * 16 + l16;
#pragma unroll
                for (int kh = 0; kh < 2; ++kh)
                    fb[tn][kh] = *reinterpret_cast<const bf16x8*>(
                        &WKs[n * 64 + (((kh * 4 + quad) ^ (n & 7)) * 8)]);
            }
#pragma unroll
            for (int kh = 0; kh < 2; ++kh)
#pragma unroll
                for (int tm = 0; tm < 4; ++tm)
#pragma unroll
                    for (int tn = 0; tn < 2; ++tn)
                        acck[tm][tn] = __builtin_amdgcn_mfma_f32_16x16x32_bf16(
                            fa[tm][kh], fb[tn][kh], acck[tm][tn], 0, 0, 0);
#pragma unroll
            for (int tm = 0; tm < 4; ++tm) {
                const int m = wm * 64 + tm * 16 + l16;
#pragma unroll
                for (int kh = 0; kh < 2; ++kh)
                    fa[tm][kh] = *reinterpret_cast<const bf16x8*>(
                        &Vs[m * 64 + (((kh * 4 + quad) ^ (m & 7)) * 8)]);
            }
#pragma unroll
            for (int tn = 0; tn < 2; ++tn) {
                const int n = wn * 32 + tn * 16 + l16;
#pragma unroll
                for (int kh = 0; kh < 2; ++kh)
                    fb[tn][kh] = *reinterpret_cast<const bf16x8*>(
                        &WVs[n * 64 + (((kh * 4 + quad) ^ (n & 7)) * 8)]);
            }
#pragma unroll
            for (int kh = 0; kh < 2; ++kh)
#pragma unroll
                for (int tm = 0; tm < 4; ++tm)
#pragma unroll
                    for (int tn = 0; tn < 2; ++tn)
                        accv[tm][tn] = __builtin_amdgcn_mfma_f32_16x16x32_bf16(
                            fa[tm][kh], fb[tn][kh], accv[tm][tn], 0, 0, 0);
            __syncthreads();
        }

        // epilogue: write kv (bf16) and accumulate 32-row chunk partials
        float part[2][2] = {{0.f, 0.f}, {0.f, 0.f}};   // [tn][tm>>1]
#pragma unroll
        for (int tm = 0; tm < 4; ++tm) {
            const long row0 = arow0 + wm * 64 + tm * 16 + quad * 4;
#pragma unroll
            for (int tn = 0; tn < 2; ++tn) {
                const int col = (int)brow0 + wn * 32 + tn * 16 + l16;
                const float bkc = bwk[col];
                const float bvc = bwv[col];
#pragma unroll
                for (int r = 0; r < 4; ++r) {
                    const float kp = fmaxf(acck[tm][tn][r] + bkc, 0.f);
                    const float vp = accv[tm][tn][r] + bvc;
                    const __bf16 kb = (__bf16)(kp * vp);
                    kvb[(row0 + r) * D + col] = kb;
                    part[tn][tm >> 1] += (float)kb;
                }
            }
        }
        // reduce over quads (rows within the 32-row chunk) and store Csum
#pragma unroll
        for (int tn = 0; tn < 2; ++tn)
#pragma unroll
            for (int th = 0; th < 2; ++th) {
                float vv = part[tn][th];
                vv += __shfl_xor(vv, 16, 64);
                vv += __shfl_xor(vv, 32, 64);
                if (quad == 0) {
                    const int fc = ((int)(arow0 >> 5)) + wm * 2 + th; // flat chunk
                    const int bb = fc / NCH;
                    const int cc = fc - bb * NCH;
                    const int col = (int)brow0 + wn * 32 + tn * 16 + l16;
                    Csum[((long)bb * NCH + cc) * D + col] = vv;
                }
            }
    }
}

// ---------------------------------------------------------------------------
// Kernel 3: sliding window (1024) via chunk-sum init + rolling edges,
// times relu(qp).  TI=32 query rows/block, 2 cols/thread.
// ---------------------------------------------------------------------------
__global__ __launch_bounds__(256) void window_kernel(
    const __bf16* __restrict__ kv, const float* __restrict__ Csum,
    const __bf16* __restrict__ qpb, float* __restrict__ out)
{
    const int iq   = blockIdx.x;        // 0..127
    const int b    = blockIdx.y;
    const int i0   = iq * TI;
    const int col2 = threadIdx.x * 2;

    const float* cs = Csum + (long)b * NCH * D + col2;
    float s0 = 0.f, s1 = 0.f;
#pragma unroll
    for (int c = 0; c < 32; ++c) {
        const float2 cv = *reinterpret_cast<const float2*>(cs + (long)(iq + c) * D);
        s0 += cv.x; s1 += cv.y;
    }

    const __bf16* kvb = kv  + (long)b * LKP * D + col2;
    const __bf16* qb  = qpb + (long)b * LQ  * D + col2;
    float*        ob  = out + (long)b * LQ  * D + col2;

#pragma unroll 8
    for (int i = i0; i < i0 + TI; ++i) {
        const bf16x2 qv = *reinterpret_cast<const bf16x2*>(qb + (long)i * D);
        *reinterpret_cast<float2*>(ob + (long)i * D) =
            make_float2((float)qv[0] * s0, (float)qv[1] * s1);
        const bf16x2 lead  = *reinterpret_cast<const bf16x2*>(kvb + (long)(i + CACHE) * D);
        const bf16x2 trail = *reinterpret_cast<const bf16x2*>(kvb + (long)i * D);
        s0 += (float)lead[0] - (float)trail[0];
        s1 += (float)lead[1] - (float)trail[1];
    }
}

// ---------------------------------------------------------------------------
extern "C" void kernel_launch(void* const* d_in, const int* in_sizes, int n_in,
                              void* d_out, int out_size, void* d_ws, size_t ws_size,
                              hipStream_t stream)
{
    const float* q   = (const float*)d_in[0];
    const float* k   = (const float*)d_in[1];
    const float* v   = (const float*)d_in[2];
    const float* gq  = (const float*)d_in[3];
    const float* bq  = (const float*)d_in[4];
    const float* gk  = (const float*)d_in[5];
    const float* bk  = (const float*)d_in[6];
    const float* gv  = (const float*)d_in[7];
    const float* bv  = (const float*)d_in[8];
    const float* Wq  = (const float*)d_in[9];
    const float* bwq = (const float*)d_in[10];
    const float* Wk  = (const float*)d_in[11];
    const float* bwk = (const float*)d_in[12];
    const float* Wv  = (const float*)d_in[13];
    const float* bwv = (const float*)d_in[14];
    float* out = (float*)d_out;

    // Workspace layout (k/v-side tensors per-batch padded: stride LKP rows)
    char* ws = (char*)d_ws;
    __bf16* qn   = (__bf16*)ws;                      // [MQ ][D] bf16
    __bf16* kn   = qn  + (long)MQ  * D;              // [MKP][D] bf16 (padded)
    __bf16* vn   = kn  + (long)MKP * D;              // [MKP][D] bf16 (padded)
    __bf16* qpb  = vn  + (long)MKP * D;              // [MQ ][D] bf16  relu(qp)
    __bf16* kvb  = qpb + (long)MQ  * D;              // [MKP][D] bf16 (padded)
    __bf16* wtq  = kvb + (long)MKP * D;              // [D][D] bf16 transposed
    __bf16* wtk  = wtq + (long)D * D;
    __bf16* wtv  = wtk + (long)D * D;
    float*  Csum = (float*)(wtv + (long)D * D);      // [B][NCH][D] f32

    // 1) LN(q,k,v) + weight transpose in ONE dispatch
    prep_kernel<<<dim3(2560, 4), 256, 0, stream>>>(
        q, k, v, gq, bq, gk, bk, gv, bv, Wq, Wk, Wv,
        qn, kn, vn, wtq, wtk, wtv);

    // 2) qp-GEMM + kv-dual-GEMM (+ fused chunk sums) in ONE dispatch
    gemm_fused_kernel<<<512 + 1280, 256, 0, stream>>>(
        qn, kn, vn, wtq, wtk, wtv, bwq, bwk, bwv, qpb, kvb, Csum);

    // 3) window sum x relu(qp)
    window_kernel<<<dim3(LQ / TI, B), 256, 0, stream>>>(kvb, Csum, qpb, out);
}